// Round 3
// baseline (364.308 us; speedup 1.0000x reference)
//
#include <hip/hip_runtime.h>
#include <stdint.h>

#define IN_F   4096
#define OUT_F  4096
#define BATCH  4096

#define BM 128
#define BN 128
#define BK 32
#define STAGES 3
#define KSTEPS (IN_F / BK)   // 128

typedef __bf16 bf16x8 __attribute__((ext_vector_type(8)));
typedef float  f32x4  __attribute__((ext_vector_type(4)));
typedef unsigned short u16x8 __attribute__((ext_vector_type(8)));

// s_waitcnt imm: vmcnt[3:0] | expcnt[6:4] | lgkmcnt[11:8] | vmcnt[5:4]@[15:14]
// lgkmcnt=0xF, expcnt=7 => don't wait on those.
#define VMCNT_IMM(n) (((n) & 15) | (((n) >> 4) << 14) | (0x7 << 4) | (0xF << 8))

// ---------- fp32 -> bf16 (RNE) ----------
__device__ inline unsigned short f32_to_bf16_rne(float f) {
    unsigned int u = __float_as_uint(f);
    u += 0x7FFFu + ((u >> 16) & 1u);
    return (unsigned short)(u >> 16);
}

__global__ void cvt2_f32_bf16(const float4* __restrict__ xa,
                              const float4* __restrict__ wa,
                              u16x8* __restrict__ xo,
                              u16x8* __restrict__ wo, int n8_per) {
    int i = blockIdx.x * blockDim.x + threadIdx.x;
    const float4* src;
    u16x8* dst;
    if (i < n8_per) { src = xa; dst = xo; }
    else            { src = wa; dst = wo; i -= n8_per; }
    float4 v0 = src[2 * i];
    float4 v1 = src[2 * i + 1];
    u16x8 o;
    o[0] = f32_to_bf16_rne(v0.x); o[1] = f32_to_bf16_rne(v0.y);
    o[2] = f32_to_bf16_rne(v0.z); o[3] = f32_to_bf16_rne(v0.w);
    o[4] = f32_to_bf16_rne(v1.x); o[5] = f32_to_bf16_rne(v1.y);
    o[6] = f32_to_bf16_rne(v1.z); o[7] = f32_to_bf16_rne(v1.w);
    dst[i] = o;
}

// ---------- async global->LDS, 16B per lane; LDS dest = base + 16*lane ----------
__device__ __forceinline__ void dma16(const unsigned short* g, unsigned short* l) {
    __builtin_amdgcn_global_load_lds(
        (const __attribute__((address_space(1))) unsigned int*)g,
        (__attribute__((address_space(3))) unsigned int*)l, 16, 0, 0);
}

// ---------- warp-specialized producer/consumer GEMM: C = A * Bt^T + bias ----------
// 5 waves: wv 0..3 consumers (2x2 of 64x64), wv 4 producer.
// 3-stage LDS ring; producer paces with s_waitcnt vmcnt(16) (never 0 in loop).
__global__ __launch_bounds__(320)
void gemm_bt_bf16(const unsigned short* __restrict__ A,
                  const unsigned short* __restrict__ Bt,
                  const float* __restrict__ bias,
                  float* __restrict__ out) {
    // stg[stage][0]=A-tile 128x32, stg[stage][1]=B-tile 128x32 (row*BK+col elems)
    __shared__ __align__(16) unsigned short stg[STAGES][2][BM * BK]; // 48 KB
    __shared__ int flags[8]; // [0]=ready (stages landed), [1..4]=cdone per consumer

    const int tid  = threadIdx.x;
    const int lane = tid & 63;
    const int wv   = tid >> 6;          // 0..4

    const int m0 = blockIdx.y * BM;
    const int n0 = blockIdx.x * BN;

    if (tid == 0) {
        flags[0] = 0; flags[1] = 0; flags[2] = 0; flags[3] = 0; flags[4] = 0;
    }
    __syncthreads();

    if (wv == 4) {
        // ---------------- PRODUCER ----------------
        const int srow  = lane >> 2;       // 0..15
        const int chunk = lane & 3;        // 8-elem k-chunk
        const unsigned short* pA = A  + (size_t)(m0 + srow) * IN_F + chunk * 8;
        const unsigned short* pB = Bt + (size_t)(n0 + srow) * IN_F + chunk * 8;

        // prologue: stages 0..2
        #pragma unroll
        for (int s = 0; s < STAGES; ++s) {
            #pragma unroll
            for (int d = 0; d < 8; ++d)
                dma16(pA + s * BK + (size_t)d * 16 * IN_F, &stg[s][0][d * 16 * BK]);
            #pragma unroll
            for (int d = 0; d < 8; ++d)
                dma16(pB + s * BK + (size_t)d * 16 * IN_F, &stg[s][1][d * 16 * BK]);
        }
        pA += STAGES * BK;
        pB += STAGES * BK;

        int slot = 0;
        for (int kt = STAGES; kt < KSTEPS; ++kt) {
            // stages <= kt-2 landed (only stage kt-1 still in flight)
            __builtin_amdgcn_s_waitcnt(VMCNT_IMM(16));
            __hip_atomic_store(&flags[0], kt - 1, __ATOMIC_RELAXED,
                               __HIP_MEMORY_SCOPE_WORKGROUP);
            // buffer reuse: need stage kt-3 consumed by all -> cdone >= kt-2
            const int need = kt - 2;
            for (;;) {
                int c0 = __hip_atomic_load(&flags[1], __ATOMIC_RELAXED, __HIP_MEMORY_SCOPE_WORKGROUP);
                int c1 = __hip_atomic_load(&flags[2], __ATOMIC_RELAXED, __HIP_MEMORY_SCOPE_WORKGROUP);
                int c2 = __hip_atomic_load(&flags[3], __ATOMIC_RELAXED, __HIP_MEMORY_SCOPE_WORKGROUP);
                int c3 = __hip_atomic_load(&flags[4], __ATOMIC_RELAXED, __HIP_MEMORY_SCOPE_WORKGROUP);
                int cmin = min(min(c0, c1), min(c2, c3));
                if (cmin >= need) break;
            }
            #pragma unroll
            for (int d = 0; d < 8; ++d)
                dma16(pA + (size_t)d * 16 * IN_F, &stg[slot][0][d * 16 * BK]);
            #pragma unroll
            for (int d = 0; d < 8; ++d)
                dma16(pB + (size_t)d * 16 * IN_F, &stg[slot][1][d * 16 * BK]);
            pA += BK; pB += BK;
            slot = (slot == STAGES - 1) ? 0 : slot + 1;
        }
        // tail: publish last two stages
        __builtin_amdgcn_s_waitcnt(VMCNT_IMM(16));
        __hip_atomic_store(&flags[0], KSTEPS - 1, __ATOMIC_RELAXED,
                           __HIP_MEMORY_SCOPE_WORKGROUP);
        __builtin_amdgcn_s_waitcnt(VMCNT_IMM(0));
        __hip_atomic_store(&flags[0], KSTEPS, __ATOMIC_RELAXED,
                           __HIP_MEMORY_SCOPE_WORKGROUP);
        return;
    }

    // ---------------- CONSUMERS ----------------
    const int wm = (wv & 1) * 64;
    const int wn = (wv >> 1) * 64;
    const int fr = lane & 15;
    const int kq = (lane >> 4) * 8;

    f32x4 acc[4][4] = {};

    int slot = 0;
    for (int kt = 0; kt < KSTEPS; ++kt) {
        // wait until stage kt landed (acquire: orders the frag reads below)
        while (__hip_atomic_load(&flags[0], __ATOMIC_ACQUIRE,
                                 __HIP_MEMORY_SCOPE_WORKGROUP) < kt + 1) { }

        bf16x8 aF[4], bF[4];
        #pragma unroll
        for (int i = 0; i < 4; ++i)
            aF[i] = *(const bf16x8*)&stg[slot][0][(wm + i * 16 + fr) * BK + kq];
        #pragma unroll
        for (int j = 0; j < 4; ++j)
            bF[j] = *(const bf16x8*)&stg[slot][1][(wn + j * 16 + fr) * BK + kq];

        #pragma unroll
        for (int i = 0; i < 4; ++i)
            #pragma unroll
            for (int j = 0; j < 4; ++j)
                acc[i][j] = __builtin_amdgcn_mfma_f32_16x16x32_bf16(
                    aF[i], bF[j], acc[i][j], 0, 0, 0);

        // release: lgkmcnt(0) drain => our ds_reads retired before signaling
        __hip_atomic_store(&flags[1 + wv], kt + 1, __ATOMIC_RELEASE,
                           __HIP_MEMORY_SCOPE_WORKGROUP);
        slot = (slot == STAGES - 1) ? 0 : slot + 1;
    }

    // Epilogue. C/D layout (m89/m91): col = lane&15, row = (lane>>4)*4 + reg
    const int ocol = n0 + wn;
    float bj[4];
    #pragma unroll
    for (int j = 0; j < 4; ++j) bj[j] = bias[ocol + j * 16 + fr];

    const int rsel = (lane >> 4) * 4;
    #pragma unroll
    for (int i = 0; i < 4; ++i) {
        #pragma unroll
        for (int v = 0; v < 4; ++v) {
            const int row = m0 + wm + i * 16 + rsel + v;
            float* orow = out + (size_t)row * OUT_F + ocol + fr;
            #pragma unroll
            for (int j = 0; j < 4; ++j)
                orow[j * 16] = acc[i][j][v] + bj[j];
        }
    }
}

// ---------- fallback: correct fp32 tiled GEMM (only if ws too small) ----------
__global__ void fb_gemm(const float* __restrict__ A, const float* __restrict__ W,
                        const float* __restrict__ bias, float* __restrict__ out) {
    __shared__ float tA[16][17];
    __shared__ float tW[16][17];
    const int tx = threadIdx.x, ty = threadIdx.y;
    const int row = blockIdx.y * 16 + ty;
    const int col = blockIdx.x * 16 + tx;
    float s = 0.f;
    for (int k = 0; k < IN_F; k += 16) {
        tA[ty][tx] = A[(size_t)row * IN_F + k + tx];
        tW[ty][tx] = W[(size_t)(blockIdx.x * 16 + ty) * IN_F + k + tx];
        __syncthreads();
        #pragma unroll
        for (int kk = 0; kk < 16; ++kk) s += tA[ty][kk] * tW[tx][kk];
        __syncthreads();
    }
    out[(size_t)row * OUT_F + col] = s + bias[col];
}

extern "C" void kernel_launch(void* const* d_in, const int* in_sizes, int n_in,
                              void* d_out, int out_size, void* d_ws, size_t ws_size,
                              hipStream_t stream) {
    const float* x = (const float*)d_in[0];
    const float* W = (const float*)d_in[1];
    const float* b = (const float*)d_in[2];
    float* out = (float*)d_out;

    const size_t elems      = (size_t)BATCH * IN_F;
    const size_t bf16_bytes = elems * 2;

    if (ws_size >= 2 * bf16_bytes) {
        unsigned short* xb = (unsigned short*)d_ws;
        unsigned short* wb = (unsigned short*)((char*)d_ws + bf16_bytes);

        const int n8_per  = (int)(elems / 8);
        const int threads = 2 * n8_per;
        cvt2_f32_bf16<<<(threads + 255) / 256, 256, 0, stream>>>(
            (const float4*)x, (const float4*)W, (u16x8*)xb, (u16x8*)wb, n8_per);

        dim3 grid(OUT_F / BN, BATCH / BM);  // 32 x 32
        gemm_bt_bf16<<<grid, 320, 0, stream>>>(xb, wb, b, out);
    } else {
        dim3 grid(OUT_F / 16, BATCH / 16);
        fb_gemm<<<grid, dim3(16, 16), 0, stream>>>(x, W, b, out);
    }
}